// Round 3
// baseline (376.925 us; speedup 1.0000x reference)
//
#include <hip/hip_runtime.h>
#include <hip/hip_bf16.h>

typedef __hip_bfloat16 bf16;
typedef short v8s __attribute__((ext_vector_type(8)));   // 8 bf16 = 16B (4 VGPRs)
typedef float v4f __attribute__((ext_vector_type(4)));   // MFMA accumulator

#define BB   4
#define NN   1024
#define DD   512
#define NHH  8
#define DH   64

__device__ __forceinline__ void split2(float v, bf16& hi, bf16& lo) {
    hi = __float2bfloat16(v);
    lo = __float2bfloat16(v - __bfloat162float(hi));
}

__device__ __forceinline__ short f2bf_bits(float f) {
    bf16 h = __float2bfloat16(f);
    short s;
    __builtin_memcpy(&s, &h, 2);
    return s;
}

// ---------------------------------------------------------------------------
// K1: LayerNorm (f32 in) -> split bf16 hi/lo out. One block per row, 256 thr.
// ---------------------------------------------------------------------------
__global__ __launch_bounds__(256) void ln_split_kernel(
    const float* __restrict__ x, const float* __restrict__ gamma,
    const float* __restrict__ beta,
    bf16* __restrict__ c_hi, bf16* __restrict__ c_lo)
{
    int row = blockIdx.x;
    int t = threadIdx.x;
    const float* xr = x + (size_t)row * DD;
    float v0 = xr[2 * t];
    float v1 = xr[2 * t + 1];
    float s = v0 + v1;
    float sq = v0 * v0 + v1 * v1;
#pragma unroll
    for (int o = 32; o; o >>= 1) {
        s  += __shfl_down(s, o, 64);
        sq += __shfl_down(sq, o, 64);
    }
    __shared__ float red[8];
    __shared__ float mb[2];
    int wave = t >> 6, lane = t & 63;
    if (lane == 0) { red[wave] = s; red[4 + wave] = sq; }
    __syncthreads();
    if (t == 0) {
        float S  = red[0] + red[1] + red[2] + red[3];
        float SQ = red[4] + red[5] + red[6] + red[7];
        float mean = S * (1.0f / DD);
        float var  = SQ * (1.0f / DD) - mean * mean;
        mb[0] = mean;
        mb[1] = rsqrtf(var + 1e-5f);
    }
    __syncthreads();
    float mean = mb[0], rstd = mb[1];
    float y0 = (v0 - mean) * rstd * gamma[2 * t] + beta[2 * t];
    float y1 = (v1 - mean) * rstd * gamma[2 * t + 1] + beta[2 * t + 1];
    bf16 h, l;
    split2(y0, h, l);
    c_hi[(size_t)row * DD + 2 * t]     = h;
    c_lo[(size_t)row * DD + 2 * t]     = l;
    split2(y1, h, l);
    c_hi[(size_t)row * DD + 2 * t + 1] = h;
    c_lo[(size_t)row * DD + 2 * t + 1] = l;
}

// ---------------------------------------------------------------------------
// K2: dtype conversions. z=0: exo->bf16 (plain); z=1: Wq->hi/lo;
// z=2: Wk->hi/lo; z=3: Wv->bf16 (plain). 4 f32 elems per thread.
// ---------------------------------------------------------------------------
__global__ __launch_bounds__(256) void convert_kernel(
    const float* __restrict__ exo, const float* __restrict__ Wq,
    const float* __restrict__ Wk,  const float* __restrict__ Wv,
    bf16* __restrict__ exo_bf,
    bf16* __restrict__ wq_hi, bf16* __restrict__ wq_lo,
    bf16* __restrict__ wk_hi, bf16* __restrict__ wk_lo,
    bf16* __restrict__ wv_bf)
{
    int z = blockIdx.z;
    int n = (z == 0) ? BB * NN * DD : DD * DD;
    int i4 = (blockIdx.x * 256 + threadIdx.x) * 4;
    if (i4 >= n) return;
    const float* src = (z == 0) ? exo : (z == 1) ? Wq : (z == 2) ? Wk : Wv;
    float4 v = *(const float4*)(src + i4);
    float vv[4] = {v.x, v.y, v.z, v.w};
    if (z == 0 || z == 3) {
        bf16* dst = (z == 0) ? exo_bf : wv_bf;
#pragma unroll
        for (int j = 0; j < 4; ++j) dst[i4 + j] = __float2bfloat16(vv[j]);
    } else {
        bf16* dh = (z == 1) ? wq_hi : wk_hi;
        bf16* dl = (z == 1) ? wq_lo : wk_lo;
#pragma unroll
        for (int j = 0; j < 4; ++j) {
            bf16 h, l;
            split2(vv[j], h, l);
            dh[i4 + j] = h;
            dl[i4 + j] = l;
        }
    }
}

// ---------------------------------------------------------------------------
// K3: projections. z=0: q (split 3-MFMA, split output); z=1: k (same);
// z=2: v (plain bf16, stored transposed vT[b*512+col][n]).
// block 256 = 4 waves, block tile 64x64, wave tile 16x64.
// ---------------------------------------------------------------------------
__global__ __launch_bounds__(256) void proj_kernel(
    const bf16* __restrict__ c_hi, const bf16* __restrict__ c_lo,
    const bf16* __restrict__ exo_bf,
    const bf16* __restrict__ wq_hi, const bf16* __restrict__ wq_lo,
    const bf16* __restrict__ wk_hi, const bf16* __restrict__ wk_lo,
    const bf16* __restrict__ wv_bf,
    const float* __restrict__ bq, const float* __restrict__ bk,
    const float* __restrict__ bv,
    bf16* __restrict__ q_hi, bf16* __restrict__ q_lo,
    bf16* __restrict__ k_hi, bf16* __restrict__ k_lo,
    bf16* __restrict__ vT)
{
    int z = blockIdx.z;
    int lane = threadIdx.x & 63;
    int wave = threadIdx.x >> 6;
    int lr = lane & 15;
    int lq = lane >> 4;
    int row0 = blockIdx.y * 64 + wave * 16;
    int col0 = blockIdx.x * 64;

    v4f acc[4] = {};
    if (z < 2) {
        const bf16* Wh = (z == 0) ? wq_hi : wk_hi;
        const bf16* Wl = (z == 0) ? wq_lo : wk_lo;
        const bf16* xh = c_hi + (size_t)(row0 + lr) * DD + lq * 8;
        const bf16* xl = c_lo + (size_t)(row0 + lr) * DD + lq * 8;
        for (int d0 = 0; d0 < DD; d0 += 32) {
            v8s ah = *(const v8s*)(xh + d0);
            v8s al = *(const v8s*)(xl + d0);
#pragma unroll
            for (int t = 0; t < 4; ++t) {
                size_t woff = (size_t)(col0 + 16 * t + lr) * DD + d0 + lq * 8;
                v8s bh = *(const v8s*)(Wh + woff);
                v8s bl = *(const v8s*)(Wl + woff);
                acc[t] = __builtin_amdgcn_mfma_f32_16x16x32_bf16(ah, bh, acc[t], 0, 0, 0);
                acc[t] = __builtin_amdgcn_mfma_f32_16x16x32_bf16(al, bh, acc[t], 0, 0, 0);
                acc[t] = __builtin_amdgcn_mfma_f32_16x16x32_bf16(ah, bl, acc[t], 0, 0, 0);
            }
        }
        const float* bias = (z == 0) ? bq : bk;
        bf16* oh = (z == 0) ? q_hi : k_hi;
        bf16* ol = (z == 0) ? q_lo : k_lo;
#pragma unroll
        for (int t = 0; t < 4; ++t) {
            int col = col0 + 16 * t + lr;
            float bvv = bias[col];
#pragma unroll
            for (int r = 0; r < 4; ++r) {
                int row = row0 + lq * 4 + r;
                float val = acc[t][r] + bvv;
                bf16 h, l;
                split2(val, h, l);
                oh[(size_t)row * DD + col] = h;
                ol[(size_t)row * DD + col] = l;
            }
        }
    } else {
        const bf16* xp = exo_bf + (size_t)(row0 + lr) * DD + lq * 8;
        for (int d0 = 0; d0 < DD; d0 += 32) {
            v8s a = *(const v8s*)(xp + d0);
#pragma unroll
            for (int t = 0; t < 4; ++t) {
                v8s b = *(const v8s*)(wv_bf + (size_t)(col0 + 16 * t + lr) * DD + d0 + lq * 8);
                acc[t] = __builtin_amdgcn_mfma_f32_16x16x32_bf16(a, b, acc[t], 0, 0, 0);
            }
        }
#pragma unroll
        for (int t = 0; t < 4; ++t) {
            int col = col0 + 16 * t + lr;
            float bvv = bv[col];
#pragma unroll
            for (int r = 0; r < 4; ++r) {
                int row = row0 + lq * 4 + r;
                int b_ = row >> 10, n = row & (NN - 1);
                vT[((size_t)b_ * DD + col) * NN + n] =
                    __float2bfloat16(acc[t][r] + bvv);
            }
        }
    }
}

// ---------------------------------------------------------------------------
// K4: scores = q@k^T * scale (split 3-MFMA), softmax, * adj -> dist (f32 out)
// block 256 per (b,h,16-row strip); wave w covers cols [256w,256w+256).
// ---------------------------------------------------------------------------
__global__ __launch_bounds__(256) void attn_scores_kernel(
    const bf16* __restrict__ q_hi, const bf16* __restrict__ q_lo,
    const bf16* __restrict__ k_hi, const bf16* __restrict__ k_lo,
    const float* __restrict__ adj, float* __restrict__ dist)
{
    __shared__ float sm[16 * NN];   // 64 KB
    int i0 = blockIdx.x * 16;
    int h  = blockIdx.y;
    int b  = blockIdx.z;
    int lane = threadIdx.x & 63;
    int wave = threadIdx.x >> 6;
    int lr = lane & 15, lq = lane >> 4;

    size_t qoff = (size_t)(b * NN + i0 + lr) * DD + h * DH + lq * 8;
    size_t kbase = (size_t)(b * NN) * DD + h * DH + lq * 8;

    v4f acc[16] = {};
#pragma unroll
    for (int kk = 0; kk < 2; ++kk) {
        v8s ah = *(const v8s*)(q_hi + qoff + kk * 32);
        v8s al = *(const v8s*)(q_lo + qoff + kk * 32);
#pragma unroll
        for (int t = 0; t < 16; ++t) {
            int col = wave * 256 + t * 16 + lr;
            size_t koff = kbase + (size_t)col * DD + kk * 32;
            v8s bh = *(const v8s*)(k_hi + koff);
            v8s bl = *(const v8s*)(k_lo + koff);
            acc[t] = __builtin_amdgcn_mfma_f32_16x16x32_bf16(ah, bh, acc[t], 0, 0, 0);
            acc[t] = __builtin_amdgcn_mfma_f32_16x16x32_bf16(al, bh, acc[t], 0, 0, 0);
            acc[t] = __builtin_amdgcn_mfma_f32_16x16x32_bf16(ah, bl, acc[t], 0, 0, 0);
        }
    }
    const float scale = 0.04419417382415922f;  // 1/sqrt(512)
#pragma unroll
    for (int t = 0; t < 16; ++t) {
        int col = wave * 256 + t * 16 + lr;
#pragma unroll
        for (int r = 0; r < 4; ++r) {
            sm[(lq * 4 + r) * NN + col] = acc[t][r] * scale;
        }
    }
    __syncthreads();

    for (int rr = 0; rr < 4; ++rr) {
        int row = wave * 4 + rr;
        float* srow = sm + row * NN;
        float mx = -1e30f;
#pragma unroll
        for (int ii = 0; ii < 16; ++ii) mx = fmaxf(mx, srow[lane + ii * 64]);
#pragma unroll
        for (int o = 32; o; o >>= 1) mx = fmaxf(mx, __shfl_xor(mx, o, 64));
        float ssum = 0.0f;
#pragma unroll
        for (int ii = 0; ii < 16; ++ii) {
            float e = __expf(srow[lane + ii * 64] - mx);
            srow[lane + ii * 64] = e;
            ssum += e;
        }
#pragma unroll
        for (int o = 32; o; o >>= 1) ssum += __shfl_xor(ssum, o, 64);
        float inv = 1.0f / ssum;
        int gi = i0 + row;
        const float* arow = adj + (size_t)gi * NN;
        float* drow = dist + (((size_t)(b * NHH + h) * NN) + gi) * NN;
#pragma unroll
        for (int ii = 0; ii < 16; ++ii) {
            int cc = lane + ii * 64;
            drow[cc] = srow[cc] * inv * arow[cc];
        }
    }
}

// ---------------------------------------------------------------------------
// K5: att[b,i,h*64+d] = sum_m dist[b,h,i,m] * v[b,m,h*64+d]
// dist is f32 (d_out); convert to bf16 A-fragments in-register. att f32 out.
// ---------------------------------------------------------------------------
__global__ __launch_bounds__(256) void attv_kernel(
    const float* __restrict__ dist, const bf16* __restrict__ vT,
    float* __restrict__ att)
{
    int bh = blockIdx.y;
    int b = bh >> 3, h = bh & 7;
    int lane = threadIdx.x & 63;
    int wave = threadIdx.x >> 6;
    int lr = lane & 15, lq = lane >> 4;
    int r0 = blockIdx.x * 64 + wave * 16;

    const float* abase = dist + ((size_t)bh * NN + r0 + lr) * NN + lq * 8;
    const bf16* bbase = vT + ((size_t)b * DD + h * DH + lr) * NN + lq * 8;

    v4f acc[4] = {};
    for (int m0 = 0; m0 < NN; m0 += 32) {
        float4 f0 = *(const float4*)(abase + m0);
        float4 f1 = *(const float4*)(abase + m0 + 4);
        v8s a;
        a[0] = f2bf_bits(f0.x); a[1] = f2bf_bits(f0.y);
        a[2] = f2bf_bits(f0.z); a[3] = f2bf_bits(f0.w);
        a[4] = f2bf_bits(f1.x); a[5] = f2bf_bits(f1.y);
        a[6] = f2bf_bits(f1.z); a[7] = f2bf_bits(f1.w);
#pragma unroll
        for (int t = 0; t < 4; ++t) {
            v8s bb = *(const v8s*)(bbase + (size_t)t * 16 * NN + m0);
            acc[t] = __builtin_amdgcn_mfma_f32_16x16x32_bf16(a, bb, acc[t], 0, 0, 0);
        }
    }
#pragma unroll
    for (int t = 0; t < 4; ++t) {
#pragma unroll
        for (int r = 0; r < 4; ++r) {
            int row = r0 + lq * 4 + r;
            att[((size_t)b * NN + row) * DD + h * DH + t * 16 + lr] = acc[t][r];
        }
    }
}

// ---------------------------------------------------------------------------
extern "C" void kernel_launch(void* const* d_in, const int* in_sizes, int n_in,
                              void* d_out, int out_size, void* d_ws, size_t ws_size,
                              hipStream_t stream)
{
    const float* user_exo = (const float*)d_in[0];
    const float* exo      = (const float*)d_in[1];
    const float* adj      = (const float*)d_in[2];
    const float* Wq       = (const float*)d_in[3];
    const float* bq       = (const float*)d_in[4];
    const float* Wk       = (const float*)d_in[5];
    const float* bk       = (const float*)d_in[6];
    const float* Wv       = (const float*)d_in[7];
    const float* bv       = (const float*)d_in[8];
    const float* gamma    = (const float*)d_in[9];
    const float* beta     = (const float*)d_in[10];

    float* att  = (float*)d_out;                     // [4,1024,512] f32
    float* dist = att + (size_t)BB * NN * DD;        // [4,8,1024,1024] f32

    const size_t NE = (size_t)BB * NN * DD;          // 2M elems
    const size_t WE = (size_t)DD * DD;               // 256K elems
    bf16* p = (bf16*)d_ws;
    bf16* c_hi   = p; p += NE;
    bf16* c_lo   = p; p += NE;
    bf16* exo_bf = p; p += NE;
    bf16* q_hi   = p; p += NE;
    bf16* q_lo   = p; p += NE;
    bf16* k_hi   = p; p += NE;
    bf16* k_lo   = p; p += NE;
    bf16* vT     = p; p += NE;                       // [4,512,1024]
    bf16* wq_hi  = p; p += WE;
    bf16* wq_lo  = p; p += WE;
    bf16* wk_hi  = p; p += WE;
    bf16* wk_lo  = p; p += WE;
    bf16* wv_bf  = p; p += WE;

    ln_split_kernel<<<BB * NN, 256, 0, stream>>>(user_exo, gamma, beta, c_hi, c_lo);
    convert_kernel<<<dim3((BB * NN * DD / 4 + 255) / 256, 1, 4), 256, 0, stream>>>(
        exo, Wq, Wk, Wv, exo_bf, wq_hi, wq_lo, wk_hi, wk_lo, wv_bf);
    proj_kernel<<<dim3(DD / 64, BB * NN / 64, 3), 256, 0, stream>>>(
        c_hi, c_lo, exo_bf, wq_hi, wq_lo, wk_hi, wk_lo, wv_bf,
        bq, bk, bv, q_hi, q_lo, k_hi, k_lo, vT);
    attn_scores_kernel<<<dim3(NN / 16, NHH, BB), 256, 0, stream>>>(
        q_hi, q_lo, k_hi, k_lo, adj, dist);
    attv_kernel<<<dim3(NN / 64, BB * NHH), 256, 0, stream>>>(dist, vT, att);
}